// Round 1
// 432.236 us; speedup vs baseline: 1.0108x; 1.0108x over previous
//
#include <hip/hip_runtime.h>

// Problem constants (from reference):
// B=256, D=8192, S=8, W=4, NSLOTS=2048, STATE_LEN=3
#define BB 256
#define DD 8192
#define SS 8
#define NSLOTS 2048
#define STATE_LEN 3

// Grid layout (flat):
//   blocks [0, CONV_BLOCKS)            : conv path, gridded by batch.
//       b = bid>>5, dchunk = bid&31  (256 d per chunk)
//   blocks [CONV_BLOCKS, +COPY_BLOCKS) : state copy for un-updated slots.
//       slot = cid/6, chunk = cid%6; 6 chunks x 1024 float4 = 24576 floats/slot
// Traffic: 64R(x) + 192R(states) + 64W(out) + 192W(new_states) = 512 MiB.
#define CONV_BLOCKS (BB * (DD / 256))       // 8192
#define COPY_CHUNKS 6
#define COPY_BLOCKS (NSLOTS * COPY_CHUNKS)  // 12288

typedef float f4 __attribute__((ext_vector_type(4)));

// ---------------------------------------------------------------------------
// Setup: flag[n] = 1 iff slot n is updated by some (valid) batch.
// One block; init-then-scatter separated by a block barrier.
// ---------------------------------------------------------------------------
__global__ __launch_bounds__(256)
void build_flags(const int* __restrict__ cache_indices,
                 const int* __restrict__ pad_p,
                 int* __restrict__ flag) {
    const int t = threadIdx.x;
#pragma unroll
    for (int k = 0; k < NSLOTS / 256; ++k) flag[t + k * 256] = 0;
    __syncthreads();
    const int ci = cache_indices[t];
    if (ci != pad_p[0] && ci >= 0 && ci < NSLOTS) flag[ci] = 1;
}

// ---------------------------------------------------------------------------
// Main fused kernel: conv+residual+state-update (by batch) and slot copy
// (by slot) in one launch so both memory phases overlap. No barriers.
// ---------------------------------------------------------------------------
__global__ __launch_bounds__(256)
void fused_conv_state_kernel(const float* __restrict__ x,
                             const float* __restrict__ weight,
                             const float* __restrict__ conv_states,
                             const int* __restrict__ cache_indices,
                             const int* __restrict__ residual_p,
                             const int* __restrict__ pad_p,
                             const int* __restrict__ flag,
                             float* __restrict__ out,
                             float* __restrict__ out_ns) {
    const int bid = blockIdx.x;
    const int tid = threadIdx.x;

    if (bid >= CONV_BLOCKS) {
        // ---- copy path: un-updated slot states, streamed nontemporally ----
        const int cid = bid - CONV_BLOCKS;
        const int n   = cid / COPY_CHUNKS;
        const int c   = cid - n * COPY_CHUNKS;
        if (flag[n]) return;                     // slot overwritten by conv path
        const size_t base4 = (size_t)n * (DD * STATE_LEN / 4)   // 6144
                           + (size_t)c * 1024 + tid;
        const f4* __restrict__ src = (const f4*)conv_states;
        f4* __restrict__ dst = (f4*)out_ns;
#pragma unroll
        for (int k = 0; k < 4; ++k) {
            f4 v = __builtin_nontemporal_load(src + base4 + k * 256);
            __builtin_nontemporal_store(v, dst + base4 + k * 256);
        }
        return;
    }

    // ---- conv path: one batch-row chunk of 256 d ----
    const int b      = bid >> 5;
    const int dchunk = bid & 31;
    const int d      = (dchunk << 8) | tid;

    const int  ci    = cache_indices[b];         // block-uniform
    const bool valid = (ci != pad_p[0]);
    const int  slot  = valid ? ci : 0;           // reference's safe_idx

    const size_t sbase = ((size_t)slot * DD + d) * STATE_LEN;
    const float s0 = conv_states[sbase];
    const float s1 = conv_states[sbase + 1];
    const float s2 = conv_states[sbase + 2];

    const f4* __restrict__ xr = (const f4*)(x + ((size_t)b * DD + d) * SS);
    const f4 x0 = xr[0];
    const f4 x1 = xr[1];
    const f4 wv = ((const f4*)weight)[d];

    const float cat[11] = {s0, s1, s2,
                           x0.x, x0.y, x0.z, x0.w,
                           x1.x, x1.y, x1.z, x1.w};
    float o[8];
#pragma unroll
    for (int s = 0; s < SS; ++s) {
        o[s] = cat[s] * wv.x + cat[s + 1] * wv.y +
               cat[s + 2] * wv.z + cat[s + 3] * wv.w;
    }
    if (residual_p[0]) {
        o[0] += x0.x; o[1] += x0.y; o[2] += x0.z; o[3] += x0.w;
        o[4] += x1.x; o[5] += x1.y; o[6] += x1.z; o[7] += x1.w;
    }

    f4* __restrict__ orow = (f4*)(out + ((size_t)b * DD + d) * SS);
    orow[0] = (f4){o[0], o[1], o[2], o[3]};
    orow[1] = (f4){o[4], o[5], o[6], o[7]};

    if (valid) {
        // new state = x[..., 5:8]
        out_ns[sbase]     = x1.y;
        out_ns[sbase + 1] = x1.z;
        out_ns[sbase + 2] = x1.w;
    }
}

extern "C" void kernel_launch(void* const* d_in, const int* in_sizes, int n_in,
                              void* d_out, int out_size, void* d_ws, size_t ws_size,
                              hipStream_t stream) {
    const float* x           = (const float*)d_in[0];
    const float* weight      = (const float*)d_in[1];
    const float* conv_states = (const float*)d_in[2];
    const int*   cache_idx   = (const int*)d_in[3];
    const int*   residual_p  = (const int*)d_in[4];
    const int*   pad_p       = (const int*)d_in[5];

    float* out    = (float*)d_out;                 // B*D*S floats
    float* out_ns = out + (size_t)BB * DD * SS;    // NSLOTS*D*STATE_LEN floats
    int*   flag   = (int*)d_ws;                    // NSLOTS ints (8 KB)

    build_flags<<<1, 256, 0, stream>>>(cache_idx, pad_p, flag);
    fused_conv_state_kernel<<<CONV_BLOCKS + COPY_BLOCKS, 256, 0, stream>>>(
        x, weight, conv_states, cache_idx, residual_p, pad_p, flag, out, out_ns);
}